// Round 20
// baseline (376.343 us; speedup 1.0000x reference)
//
#include <hip/hip_runtime.h>
#include <hip/hip_fp16.h>

#define NN 100000
#define NE 3200000
#define NFEAT 256
#define HDIM 64
#define NCLASS 64
#define ALPHA 0.1f
#define CAP 80             // fixed col row stride; P(deg>80)~1e-11 (Poisson mean 32)

#define NB 256             // dst buckets
#define BKN 391            // nodes per bucket (391*256 = 100096 >= NN); d_local < 512 (9 bits)
#define EBLK (NE / 256)    // 12500 edges per stage-A block
#define BCAP 24            // LDS per-batch per-bucket capacity (mean 4, z~10)
#define RCAP 96            // region per-(block,bucket) capacity (mean 48.8, z~6.8)

typedef _Float16 half8 __attribute__((ext_vector_type(8)));
typedef float f32x4 __attribute__((ext_vector_type(4)));

// ---------------- fp8 helpers (gfx950 OCP e4m3 via HW cvt) ----------------

__device__ inline unsigned pack4_fp8(float a, float b, float c, float d) {
    unsigned v = 0;
    v = __builtin_amdgcn_cvt_pk_fp8_f32(a, b, v, false);   // bytes 0,1
    v = __builtin_amdgcn_cvt_pk_fp8_f32(c, d, v, true);    // bytes 2,3
    return v;
}

// unpack+accumulate 4 fp8 (one uint) with mask m
__device__ inline void acc4_fp8(unsigned r, float m, float* acc) {
    auto lo = __builtin_amdgcn_cvt_pk_f32_fp8(r, false);
    auto hi = __builtin_amdgcn_cvt_pk_f32_fp8(r, true);
    acc[0] = fmaf(m, lo[0], acc[0]); acc[1] = fmaf(m, lo[1], acc[1]);
    acc[2] = fmaf(m, hi[0], acc[2]); acc[3] = fmaf(m, hi[1], acc[3]);
}

// ---------------- Stage A: partition edges into 256 dst-range buckets ----------------

__global__ __launch_bounds__(1024) void bucket_edges(const int* __restrict__ ei,
                                                     unsigned* __restrict__ pairs,
                                                     int* __restrict__ cntg) {
    __shared__ unsigned buf[NB][BCAP];   // 24.6 KB
    __shared__ int cnt[NB];
    __shared__ int rcur[NB];
    int blk = blockIdx.x;
    int t = threadIdx.x;
    int e0 = blk * EBLK;
    for (int i = t; i < NB; i += 1024) { cnt[i] = 0; rcur[i] = 0; }
    __syncthreads();

    for (int eb = 0; eb < EBLK; eb += 1024) {
        bool act = (eb + t) < EBLK;
        if (act) {
            int e = e0 + eb + t;
            unsigned d = (unsigned)ei[NE + e];
            unsigned src = (unsigned)ei[e];
            unsigned b = d / BKN;
            unsigned w = (src << 9) | (d - b * BKN);
            int p = atomicAdd(&cnt[b], 1);
            if (p < BCAP) buf[b][p] = w;
        }
        __syncthreads();
        int lane = t & 63, wv = t >> 6;
        for (int j = 0; j < 16; j++) {
            int b2 = wv * 16 + j;
            int c = cnt[b2]; if (c > BCAP) c = BCAP;
            int rb = rcur[b2];
            if (lane < c) {
                int idx = rb + lane;
                if (idx < RCAP)
                    pairs[((size_t)blk * NB + b2) * RCAP + idx] = buf[b2][lane];
            }
            if (lane == 0) rcur[b2] = rb + c;
        }
        __syncthreads();
        if (t < NB) cnt[t] = 0;
        __syncthreads();
    }
    if (t < NB) cntg[blk * NB + t] = min(rcur[t], RCAP);
}

// ---------------- Stage B: per-bucket scatter + deg/dinv emission ----------------

__global__ __launch_bounds__(1024) void fill_bucket(const unsigned* __restrict__ pairs,
                                                    const int* __restrict__ cntg,
                                                    int* __restrict__ col,
                                                    int* __restrict__ deg,
                                                    float* __restrict__ dinv) {
    __shared__ int cur[BKN];
    __shared__ int pref[NB + 1];
    __shared__ int cnts[NB];
    int b = blockIdx.x;
    int t = threadIdx.x;
    unsigned lo = (unsigned)b * BKN;
    for (int i = t; i < BKN; i += 1024) cur[i] = 0;
    if (t < NB) cnts[t] = cntg[t * NB + b];
    __syncthreads();
    if (t == 0) {
        int run = 0;
        for (int k = 0; k < NB; k++) { pref[k] = run; run += cnts[k]; }
        pref[NB] = run;
    }
    __syncthreads();
    int T = pref[NB];
    for (int i0 = 0; i0 < T; i0 += 1024) {
        int i = i0 + t;
        if (i < T) {
            int l = 0, h = NB;
            while (h - l > 1) { int m = (l + h) >> 1; if (pref[m] <= i) l = m; else h = m; }
            unsigned w = pairs[((size_t)l * NB + b) * RCAP + (i - pref[l])];
            unsigned dl = w & 511;
            unsigned src = w >> 9;
            int slot = atomicAdd(&cur[dl], 1);
            if (slot < CAP && lo + dl < NN)
                col[(size_t)(lo + dl) * CAP + slot] = (int)src;
        }
    }
    __syncthreads();
    for (int i = t; i < BKN; i += 1024) {
        unsigned node = lo + i;
        if (node < NN) {
            int dgv = cur[i];
            deg[node] = dgv;
            dinv[node] = rsqrtf((float)dgv + 1.f);
        }
    }
}

// ---------------- W pack: W2g[kg][n][8] = fp16 W[n][kg*8..+7], n XOR-swizzled vs kg ----------------

__global__ void prep_w(const float* __restrict__ W, _Float16* __restrict__ W2g,
                       int KG, int Kfull) {
    int i = blockIdx.x * 256 + threadIdx.x;   // (kg, n) pairs: KG*64
    if (i >= KG * 64) return;
    int kg = i >> 6;
    int n = i & 63;
    int slot = (kg << 6) + (n ^ ((kg & 3) << 2));
    _Float16 tmp[8];
#pragma unroll
    for (int j = 0; j < 8; j++) tmp[j] = (_Float16)W[n * Kfull + kg * 8 + j];
    *(half8*)&W2g[(size_t)slot * 8] = *(half8*)tmp;
}

// ---------------- input GEMM via MFMA f16, barrier-free K-loop ----------------

__global__ __launch_bounds__(256) void gemm1_mfma(const float* __restrict__ x,
                                                  const _Float16* __restrict__ W2g,
                                                  const float* __restrict__ bias,
                                                  const float* __restrict__ dinv,
                                                  _Float16* __restrict__ g0) {
    __shared__ _Float16 W2[32 * 64 * 8];    // 32 KB
    int t = threadIdx.x;
    for (int i = t; i < 2048; i += 256)
        *(half8*)&W2[(size_t)i * 8] = *(const half8*)&W2g[(size_t)i * 8];
    __syncthreads();

    int lane = t & 63;
    int w = t >> 6;
    int r16 = lane & 15, kg = lane >> 4;
    int row0 = blockIdx.x * 128;
    int rowA = row0 + w * 32 + r16;
    int rowB = rowA + 16;
    int rA = rowA < NN ? rowA : NN - 1;
    int rB = rowB < NN ? rowB : NN - 1;
    const float* pa = &x[(size_t)rA * 256 + kg * 8];
    const float* pb = &x[(size_t)rB * 256 + kg * 8];

    f32x4 acc[2][4];
#pragma unroll
    for (int mt = 0; mt < 2; mt++)
#pragma unroll
        for (int nt = 0; nt < 4; nt++) acc[mt][nt] = (f32x4){0.f, 0.f, 0.f, 0.f};

#pragma unroll
    for (int ks = 0; ks < 8; ks++) {
        float4 va0 = *(const float4*)(pa + ks * 32);
        float4 va1 = *(const float4*)(pa + ks * 32 + 4);
        float4 vb0 = *(const float4*)(pb + ks * 32);
        float4 vb1 = *(const float4*)(pb + ks * 32 + 4);
        _Float16 a0h[8] = {(_Float16)va0.x, (_Float16)va0.y, (_Float16)va0.z, (_Float16)va0.w,
                           (_Float16)va1.x, (_Float16)va1.y, (_Float16)va1.z, (_Float16)va1.w};
        _Float16 a1h[8] = {(_Float16)vb0.x, (_Float16)vb0.y, (_Float16)vb0.z, (_Float16)vb0.w,
                           (_Float16)vb1.x, (_Float16)vb1.y, (_Float16)vb1.z, (_Float16)vb1.w};
        half8 a0 = *(half8*)a0h;
        half8 a1 = *(half8*)a1h;
        int kgg = ks * 4 + kg;
#pragma unroll
        for (int nt = 0; nt < 4; nt++) {
            int nidx = nt * 16 + r16;
            int slot = (kgg << 6) + (nidx ^ ((kgg & 3) << 2));
            half8 bfr = *(half8*)&W2[(size_t)slot * 8];
            acc[0][nt] = __builtin_amdgcn_mfma_f32_16x16x32_f16(a0, bfr, acc[0][nt], 0, 0, 0);
            acc[1][nt] = __builtin_amdgcn_mfma_f32_16x16x32_f16(a1, bfr, acc[1][nt], 0, 0, 0);
        }
    }

#pragma unroll
    for (int mt = 0; mt < 2; mt++)
#pragma unroll
        for (int nt = 0; nt < 4; nt++) {
            int colj = nt * 16 + r16;
            float bv = bias[colj];
#pragma unroll
            for (int r = 0; r < 4; r++) {
                int row = row0 + w * 32 + mt * 16 + kg * 4 + r;
                if (row < NN)
                    g0[(size_t)row * 64 + colj] = (_Float16)((acc[mt][nt][r] + bv) * dinv[row]);
            }
        }
}

// ---------------- g0 fp16 -> split fp8 halves (feats 0-31 -> a, 32-63 -> b) ----------------

__global__ __launch_bounds__(256) void cvt_split_fp8(const __half* __restrict__ in,
                                                     unsigned* __restrict__ outa,
                                                     unsigned* __restrict__ outb) {
    int i = blockIdx.x * 256 + threadIdx.x;   // one uint (4 feats) per thread
    if (i >= NN * 16) return;
    int node = i >> 4;
    int s = i & 15;
    int half = s >> 3;
    int q = s & 7;
    float2 zr = *(const float2*)&in[(size_t)node * 64 + half * 32 + q * 4];   // 4 fp16
    const __half2* zh = (const __half2*)&zr;
    float2 v0 = __half22float2(zh[0]);
    float2 v1 = __half22float2(zh[1]);
    unsigned o = pack4_fp8(v0.x, v0.y, v1.x, v1.y);
    (half ? outb : outa)[(size_t)node * 8 + q] = o;
}

// ---------------- output GEMM via MFMA f16 (K=64): out = relu(h) @ W_out^T + b ----------------

__global__ __launch_bounds__(256) void gemm2_mfma(const float* __restrict__ h,
                                                  const _Float16* __restrict__ W2o,
                                                  const float* __restrict__ bias,
                                                  float* __restrict__ out) {
    __shared__ _Float16 W2[8 * 64 * 8];   // 8 KB
    int t = threadIdx.x;
    for (int i = t; i < 512; i += 256)
        *(half8*)&W2[(size_t)i * 8] = *(const half8*)&W2o[(size_t)i * 8];
    __syncthreads();

    int lane = t & 63;
    int w = t >> 6;
    int r16 = lane & 15, kg = lane >> 4;
    int row0 = blockIdx.x * 128;
    int rowA = row0 + w * 32 + r16;
    int rowB = rowA + 16;
    int rA = rowA < NN ? rowA : NN - 1;
    int rB = rowB < NN ? rowB : NN - 1;
    const float* pa = &h[(size_t)rA * 64 + kg * 8];
    const float* pb = &h[(size_t)rB * 64 + kg * 8];

    f32x4 acc[2][4];
#pragma unroll
    for (int mt = 0; mt < 2; mt++)
#pragma unroll
        for (int nt = 0; nt < 4; nt++) acc[mt][nt] = (f32x4){0.f, 0.f, 0.f, 0.f};

#pragma unroll
    for (int ks = 0; ks < 2; ks++) {
        float4 va0 = *(const float4*)(pa + ks * 32);
        float4 va1 = *(const float4*)(pa + ks * 32 + 4);
        float4 vb0 = *(const float4*)(pb + ks * 32);
        float4 vb1 = *(const float4*)(pb + ks * 32 + 4);
        _Float16 a0h[8] = {(_Float16)fmaxf(va0.x, 0.f), (_Float16)fmaxf(va0.y, 0.f),
                           (_Float16)fmaxf(va0.z, 0.f), (_Float16)fmaxf(va0.w, 0.f),
                           (_Float16)fmaxf(va1.x, 0.f), (_Float16)fmaxf(va1.y, 0.f),
                           (_Float16)fmaxf(va1.z, 0.f), (_Float16)fmaxf(va1.w, 0.f)};
        _Float16 a1h[8] = {(_Float16)fmaxf(vb0.x, 0.f), (_Float16)fmaxf(vb0.y, 0.f),
                           (_Float16)fmaxf(vb0.z, 0.f), (_Float16)fmaxf(vb0.w, 0.f),
                           (_Float16)fmaxf(vb1.x, 0.f), (_Float16)fmaxf(vb1.y, 0.f),
                           (_Float16)fmaxf(vb1.z, 0.f), (_Float16)fmaxf(vb1.w, 0.f)};
        half8 a0 = *(half8*)a0h;
        half8 a1 = *(half8*)a1h;
        int kgg = ks * 4 + kg;
#pragma unroll
        for (int nt = 0; nt < 4; nt++) {
            int nidx = nt * 16 + r16;
            int slot = (kgg << 6) + (nidx ^ ((kgg & 3) << 2));
            half8 bfr = *(half8*)&W2[(size_t)slot * 8];
            acc[0][nt] = __builtin_amdgcn_mfma_f32_16x16x32_f16(a0, bfr, acc[0][nt], 0, 0, 0);
            acc[1][nt] = __builtin_amdgcn_mfma_f32_16x16x32_f16(a1, bfr, acc[1][nt], 0, 0, 0);
        }
    }

#pragma unroll
    for (int mt = 0; mt < 2; mt++)
#pragma unroll
        for (int nt = 0; nt < 4; nt++) {
            int colj = nt * 16 + r16;
            float bv = bias[colj];
#pragma unroll
            for (int r = 0; r < 4; r++) {
                int row = row0 + w * 32 + mt * 16 + kg * 4 + r;
                if (row < NN)
                    out[(size_t)row * 64 + colj] = acc[mt][nt][r] + bv;
            }
        }
}

// ---------------- APPNP propagation: fp8 state split in feature halves ----------------
// R19 diagnosis: 6.4MB state > 4MB per-XCD L2 -> ~55% of gathers missed L2 (FETCH 114MB).
// Split state into two 3.2MB halves; blockIdx&1 selects half -> with round-robin
// blockIdx->XCD mapping, each XCD gathers from ONE 3.2MB half = L2-resident.
// Lane map per half: eg=lane>>3 (8 edge groups), q=lane&7 (4B slot = 4 fp8 feats).
// 4 independent gathers in flight per round (32 edges).

template <bool FINAL>
__global__ __launch_bounds__(256) void appnp_prop_s(const unsigned* __restrict__ ga,
                                                    const unsigned* __restrict__ gb,
                                                    unsigned* __restrict__ na,
                                                    unsigned* __restrict__ nb,
                                                    float* __restrict__ hout,
                                                    const __half* __restrict__ g0h,
                                                    const float* __restrict__ dinv,
                                                    const int* __restrict__ deg,
                                                    const int* __restrict__ col) {
    int half = blockIdx.x & 1;
    int wid = (blockIdx.x >> 1) * 4 + (threadIdx.x >> 6);
    int lane = threadIdx.x & 63;
    if (wid >= NN) return;
    const unsigned* gc = half ? gb : ga;
    int eg = lane >> 3;    // edge group 0..7
    int q  = lane & 7;     // 4B slot (feats half*32 + 4q .. +3)

    float acc[4] = {0.f, 0.f, 0.f, 0.f};
    int dg = deg[wid]; if (dg > CAP) dg = CAP;
    int e0 = wid * CAP;
    int end = e0 + dg;
    for (int p = e0; p < end; p += 32) {   // 32 edges per round, 4 gathers in flight
        int i0 = p + eg, i1 = p + 8 + eg, i2 = p + 16 + eg, i3 = p + 24 + eg;
        float m0 = (i0 < end) ? 1.f : 0.f;
        float m1 = (i1 < end) ? 1.f : 0.f;
        float m2 = (i2 < end) ? 1.f : 0.f;
        float m3 = (i3 < end) ? 1.f : 0.f;
        int s0 = col[(i0 < end) ? i0 : end - 1];
        int s1 = col[(i1 < end) ? i1 : end - 1];
        int s2 = col[(i2 < end) ? i2 : end - 1];
        int s3 = col[(i3 < end) ? i3 : end - 1];
        unsigned r0 = gc[(size_t)s0 * 8 + q];
        unsigned r1 = gc[(size_t)s1 * 8 + q];
        unsigned r2 = gc[(size_t)s2 * 8 + q];
        unsigned r3 = gc[(size_t)s3 * 8 + q];
        acc4_fp8(r0, m0, acc);
        acc4_fp8(r1, m1, acc);
        acc4_fp8(r2, m2, acc);
        acc4_fp8(r3, m3, acc);
    }

    // butterfly reduce across the 8 edge groups (lane bits 3,4,5)
#pragma unroll
    for (int st = 8; st < 64; st <<= 1) {
#pragma unroll
        for (int j = 0; j < 4; j++) acc[j] += __shfl(acc[j], lane ^ st);
    }

    if (eg == 0) {   // lanes 0..7, lane == q; 4 feats each
        float di = dinv[wid];
        float k = (1.f - ALPHA) * di * di;
        // self term (fp8)
        unsigned sraw = gc[(size_t)wid * 8 + q];
        auto slo = __builtin_amdgcn_cvt_pk_f32_fp8(sraw, false);
        auto shi = __builtin_amdgcn_cvt_pk_f32_fp8(sraw, true);
        float sf[4] = {slo[0], slo[1], shi[0], shi[1]};
        // anchor term (fp16)
        float2 zr = *(const float2*)&g0h[(size_t)wid * 64 + half * 32 + q * 4];
        const __half2* zh = (const __half2*)&zr;
        float2 z0 = __half22float2(zh[0]);
        float2 z1 = __half22float2(zh[1]);
        float zf[4] = {z0.x, z0.y, z1.x, z1.y};
        float g[4];
#pragma unroll
        for (int j = 0; j < 4; j++)
            g[j] = k * (acc[j] + sf[j]) + ALPHA * zf[j];

        if (FINAL) {   // h = g/dinv, fp32 row-major
            float inv = 1.f / di;
            float4 o = make_float4(g[0] * inv, g[1] * inv, g[2] * inv, g[3] * inv);
            *(float4*)&hout[(size_t)wid * 64 + half * 32 + q * 4] = o;
        } else {
            (half ? nb : na)[(size_t)wid * 8 + q] = pack4_fp8(g[0], g[1], g[2], g[3]);
        }
    }
}

// ---------------- launch ----------------

extern "C" void kernel_launch(void* const* d_in, const int* in_sizes, int n_in,
                              void* d_out, int out_size, void* d_ws, size_t ws_size,
                              hipStream_t stream) {
    const float* x    = (const float*)d_in[0];
    const int*  ei    = (const int*)d_in[1];      // harness converts int64 -> int32
    const float* W_in = (const float*)d_in[2];
    const float* b_in = (const float*)d_in[3];
    const float* W_out= (const float*)d_in[4];
    const float* b_out= (const float*)d_in[5];
    float* out = (float*)d_out;

    char* ws = (char*)d_ws;
    size_t off = 0;
    auto alloc = [&](size_t bytes) -> void* {
        void* p = ws + off;
        off = (off + bytes + 255) & ~(size_t)255;
        return p;
    };
    int*      deg  = (int*)    alloc((size_t)NN * 4);
    float*    dinv = (float*)  alloc((size_t)NN * 4);
    int*      cntg = (int*)    alloc((size_t)NB * 256 * 4);       // 256 KB
    _Float16* W2g  = (_Float16*)alloc((size_t)32 * 64 * 8 * 2);   // 32 KB packed W_in
    _Float16* W2o  = (_Float16*)alloc((size_t)8 * 64 * 8 * 2);    // 8 KB packed W_out
    int*      col  = (int*)    alloc((size_t)NN * CAP * 4);       // 32 MB
    __half*   g0h  = (__half*) alloc((size_t)NN * HDIM * 2);      // 12.8 MB fp16 anchor
    unsigned* g0a  = (unsigned*)alloc((size_t)NN * 32);           // 3.2 MB fp8 half
    unsigned* g0b  = (unsigned*)alloc((size_t)NN * 32);
    unsigned* gAa  = (unsigned*)alloc((size_t)NN * 32);
    unsigned* gAb  = (unsigned*)alloc((size_t)NN * 32);
    unsigned* gBa  = (unsigned*)alloc((size_t)NN * 32);
    unsigned* gBb  = (unsigned*)alloc((size_t)NN * 32);
    // pairs (25.2MB) aliases the g region: dead before gemm1 writes g0h
    unsigned* pairs = (unsigned*)g0h;

    // CSR build: 2 kernels, zero global atomics, deg/dinv emitted by stage B
    bucket_edges<<<256, 1024, 0, stream>>>(ei, pairs, cntg);
    fill_bucket<<<NB, 1024, 0, stream>>>(pairs, cntg, col, deg, dinv);

    // weight packs
    prep_w<<<8, 256, 0, stream>>>(W_in, W2g, 32, 256);
    prep_w<<<2, 256, 0, stream>>>(W_out, W2o, 8, 64);

    // g0 = fp16((x @ W_in^T + b_in) * dinv[row]) via MFMA f16; split fp8 copies
    gemm1_mfma<<<(NN + 127) / 128, 256, 0, stream>>>(x, W2g, b_in, dinv, (_Float16*)g0h);
    cvt_split_fp8<<<(NN * 16 + 255) / 256, 256, 0, stream>>>(g0h, g0a, g0b);

    // K=4 APPNP iterations on split fp8 state; 4th writes fp32 h into d_out
    const int pgrid = 2 * (NN / 4);   // 50000 blocks: blockIdx&1 = feature half
    appnp_prop_s<false><<<pgrid, 256, 0, stream>>>(g0a, g0b, gAa, gAb, nullptr, g0h, dinv, deg, col);
    appnp_prop_s<false><<<pgrid, 256, 0, stream>>>(gAa, gAb, gBa, gBb, nullptr, g0h, dinv, deg, col);
    appnp_prop_s<false><<<pgrid, 256, 0, stream>>>(gBa, gBb, gAa, gAb, nullptr, g0h, dinv, deg, col);
    appnp_prop_s<true ><<<pgrid, 256, 0, stream>>>(gAa, gAb, nullptr, nullptr, out, g0h, dinv, deg, col);

    // out = relu(h) @ W_out^T + b_out via MFMA f16 (in-place safe per wave-span analysis)
    gemm2_mfma<<<(NN + 127) / 128, 256, 0, stream>>>(out, W2o, b_out, out);
}

// Round 21
// 287.180 us; speedup vs baseline: 1.3105x; 1.3105x over previous
//
#include <hip/hip_runtime.h>
#include <hip/hip_fp16.h>

#define NN 100000
#define NE 3200000
#define NFEAT 256
#define HDIM 64
#define NCLASS 64
#define ALPHA 0.1f
#define CAP 80             // fixed col row stride; P(deg>80)~1e-11 (Poisson mean 32)

#define NB 256             // dst buckets
#define BKN 391            // nodes per bucket (391*256 = 100096 >= NN); d_local < 512 (9 bits)
#define EBLK (NE / 256)    // 12500 edges per stage-A block
#define BCAP 24            // LDS per-batch per-bucket capacity (mean 4, z~10)
#define RCAP 96            // region per-(block,bucket) capacity (mean 48.8, z~6.8)

typedef _Float16 half8 __attribute__((ext_vector_type(8)));
typedef float f32x4 __attribute__((ext_vector_type(4)));

// ---------------- fp8 helpers (gfx950 OCP e4m3 via HW cvt) ----------------

__device__ inline unsigned pack4_fp8(float a, float b, float c, float d) {
    unsigned v = 0;
    v = __builtin_amdgcn_cvt_pk_fp8_f32(a, b, v, false);   // bytes 0,1
    v = __builtin_amdgcn_cvt_pk_fp8_f32(c, d, v, true);    // bytes 2,3
    return v;
}

// unpack+accumulate 8 fp8 (one uint2) with mask m
__device__ inline void acc8_fp8(uint2 r, float m, float* acc) {
    auto l0 = __builtin_amdgcn_cvt_pk_f32_fp8(r.x, false);
    auto h0 = __builtin_amdgcn_cvt_pk_f32_fp8(r.x, true);
    auto l1 = __builtin_amdgcn_cvt_pk_f32_fp8(r.y, false);
    auto h1 = __builtin_amdgcn_cvt_pk_f32_fp8(r.y, true);
    acc[0] = fmaf(m, l0[0], acc[0]); acc[1] = fmaf(m, l0[1], acc[1]);
    acc[2] = fmaf(m, h0[0], acc[2]); acc[3] = fmaf(m, h0[1], acc[3]);
    acc[4] = fmaf(m, l1[0], acc[4]); acc[5] = fmaf(m, l1[1], acc[5]);
    acc[6] = fmaf(m, h1[0], acc[6]); acc[7] = fmaf(m, h1[1], acc[7]);
}

// ---------------- Stage A: partition edges into 256 dst-range buckets ----------------

__global__ __launch_bounds__(1024) void bucket_edges(const int* __restrict__ ei,
                                                     unsigned* __restrict__ pairs,
                                                     int* __restrict__ cntg) {
    __shared__ unsigned buf[NB][BCAP];   // 24.6 KB
    __shared__ int cnt[NB];
    __shared__ int rcur[NB];
    int blk = blockIdx.x;
    int t = threadIdx.x;
    int e0 = blk * EBLK;
    for (int i = t; i < NB; i += 1024) { cnt[i] = 0; rcur[i] = 0; }
    __syncthreads();

    for (int eb = 0; eb < EBLK; eb += 1024) {
        bool act = (eb + t) < EBLK;
        if (act) {
            int e = e0 + eb + t;
            unsigned d = (unsigned)ei[NE + e];
            unsigned src = (unsigned)ei[e];
            unsigned b = d / BKN;
            unsigned w = (src << 9) | (d - b * BKN);
            int p = atomicAdd(&cnt[b], 1);
            if (p < BCAP) buf[b][p] = w;
        }
        __syncthreads();
        int lane = t & 63, wv = t >> 6;
        for (int j = 0; j < 16; j++) {
            int b2 = wv * 16 + j;
            int c = cnt[b2]; if (c > BCAP) c = BCAP;
            int rb = rcur[b2];
            if (lane < c) {
                int idx = rb + lane;
                if (idx < RCAP)
                    pairs[((size_t)blk * NB + b2) * RCAP + idx] = buf[b2][lane];
            }
            if (lane == 0) rcur[b2] = rb + c;
        }
        __syncthreads();
        if (t < NB) cnt[t] = 0;
        __syncthreads();
    }
    if (t < NB) cntg[blk * NB + t] = min(rcur[t], RCAP);
}

// ---------------- Stage B: per-bucket scatter + deg/dinv emission ----------------

__global__ __launch_bounds__(1024) void fill_bucket(const unsigned* __restrict__ pairs,
                                                    const int* __restrict__ cntg,
                                                    int* __restrict__ col,
                                                    int* __restrict__ deg,
                                                    float* __restrict__ dinv) {
    __shared__ int cur[BKN];
    __shared__ int pref[NB + 1];
    __shared__ int cnts[NB];
    int b = blockIdx.x;
    int t = threadIdx.x;
    unsigned lo = (unsigned)b * BKN;
    for (int i = t; i < BKN; i += 1024) cur[i] = 0;
    if (t < NB) cnts[t] = cntg[t * NB + b];
    __syncthreads();
    if (t == 0) {
        int run = 0;
        for (int k = 0; k < NB; k++) { pref[k] = run; run += cnts[k]; }
        pref[NB] = run;
    }
    __syncthreads();
    int T = pref[NB];
    for (int i0 = 0; i0 < T; i0 += 1024) {
        int i = i0 + t;
        if (i < T) {
            int l = 0, h = NB;
            while (h - l > 1) { int m = (l + h) >> 1; if (pref[m] <= i) l = m; else h = m; }
            unsigned w = pairs[((size_t)l * NB + b) * RCAP + (i - pref[l])];
            unsigned dl = w & 511;
            unsigned src = w >> 9;
            int slot = atomicAdd(&cur[dl], 1);
            if (slot < CAP && lo + dl < NN)
                col[(size_t)(lo + dl) * CAP + slot] = (int)src;
        }
    }
    __syncthreads();
    for (int i = t; i < BKN; i += 1024) {
        unsigned node = lo + i;
        if (node < NN) {
            int dgv = cur[i];
            deg[node] = dgv;
            dinv[node] = rsqrtf((float)dgv + 1.f);
        }
    }
}

// ---------------- W pack: W2g[kg][n][8] = fp16 W[n][kg*8..+7], n XOR-swizzled vs kg ----------------

__global__ void prep_w(const float* __restrict__ W, _Float16* __restrict__ W2g,
                       int KG, int Kfull) {
    int i = blockIdx.x * 256 + threadIdx.x;   // (kg, n) pairs: KG*64
    if (i >= KG * 64) return;
    int kg = i >> 6;
    int n = i & 63;
    int slot = (kg << 6) + (n ^ ((kg & 3) << 2));
    _Float16 tmp[8];
#pragma unroll
    for (int j = 0; j < 8; j++) tmp[j] = (_Float16)W[n * Kfull + kg * 8 + j];
    *(half8*)&W2g[(size_t)slot * 8] = *(half8*)tmp;
}

// ---------------- input GEMM via MFMA f16, barrier-free K-loop ----------------

__global__ __launch_bounds__(256) void gemm1_mfma(const float* __restrict__ x,
                                                  const _Float16* __restrict__ W2g,
                                                  const float* __restrict__ bias,
                                                  const float* __restrict__ dinv,
                                                  _Float16* __restrict__ g0) {
    __shared__ _Float16 W2[32 * 64 * 8];    // 32 KB
    int t = threadIdx.x;
    for (int i = t; i < 2048; i += 256)
        *(half8*)&W2[(size_t)i * 8] = *(const half8*)&W2g[(size_t)i * 8];
    __syncthreads();

    int lane = t & 63;
    int w = t >> 6;
    int r16 = lane & 15, kg = lane >> 4;
    int row0 = blockIdx.x * 128;
    int rowA = row0 + w * 32 + r16;
    int rowB = rowA + 16;
    int rA = rowA < NN ? rowA : NN - 1;
    int rB = rowB < NN ? rowB : NN - 1;
    const float* pa = &x[(size_t)rA * 256 + kg * 8];
    const float* pb = &x[(size_t)rB * 256 + kg * 8];

    f32x4 acc[2][4];
#pragma unroll
    for (int mt = 0; mt < 2; mt++)
#pragma unroll
        for (int nt = 0; nt < 4; nt++) acc[mt][nt] = (f32x4){0.f, 0.f, 0.f, 0.f};

#pragma unroll
    for (int ks = 0; ks < 8; ks++) {
        float4 va0 = *(const float4*)(pa + ks * 32);
        float4 va1 = *(const float4*)(pa + ks * 32 + 4);
        float4 vb0 = *(const float4*)(pb + ks * 32);
        float4 vb1 = *(const float4*)(pb + ks * 32 + 4);
        _Float16 a0h[8] = {(_Float16)va0.x, (_Float16)va0.y, (_Float16)va0.z, (_Float16)va0.w,
                           (_Float16)va1.x, (_Float16)va1.y, (_Float16)va1.z, (_Float16)va1.w};
        _Float16 a1h[8] = {(_Float16)vb0.x, (_Float16)vb0.y, (_Float16)vb0.z, (_Float16)vb0.w,
                           (_Float16)vb1.x, (_Float16)vb1.y, (_Float16)vb1.z, (_Float16)vb1.w};
        half8 a0 = *(half8*)a0h;
        half8 a1 = *(half8*)a1h;
        int kgg = ks * 4 + kg;
#pragma unroll
        for (int nt = 0; nt < 4; nt++) {
            int nidx = nt * 16 + r16;
            int slot = (kgg << 6) + (nidx ^ ((kgg & 3) << 2));
            half8 bfr = *(half8*)&W2[(size_t)slot * 8];
            acc[0][nt] = __builtin_amdgcn_mfma_f32_16x16x32_f16(a0, bfr, acc[0][nt], 0, 0, 0);
            acc[1][nt] = __builtin_amdgcn_mfma_f32_16x16x32_f16(a1, bfr, acc[1][nt], 0, 0, 0);
        }
    }

#pragma unroll
    for (int mt = 0; mt < 2; mt++)
#pragma unroll
        for (int nt = 0; nt < 4; nt++) {
            int colj = nt * 16 + r16;
            float bv = bias[colj];
#pragma unroll
            for (int r = 0; r < 4; r++) {
                int row = row0 + w * 32 + mt * 16 + kg * 4 + r;
                if (row < NN)
                    g0[(size_t)row * 64 + colj] = (_Float16)((acc[mt][nt][r] + bv) * dinv[row]);
            }
        }
}

// ---------------- g0 fp16 -> fp8 copy (coalesced; gather source for sweep 1) ----------------

__global__ __launch_bounds__(256) void cvt_fp16_fp8(const __half* __restrict__ in,
                                                    unsigned char* __restrict__ out) {
    int i = blockIdx.x * 256 + threadIdx.x;   // 8 feats per thread
    if (i >= NN * 8) return;
    float4 raw = ((const float4*)in)[i];
    const __half2* h2 = (const __half2*)&raw;
    float f[8];
#pragma unroll
    for (int j = 0; j < 4; j++) {
        float2 v = __half22float2(h2[j]);
        f[2 * j] = v.x; f[2 * j + 1] = v.y;
    }
    uint2 o;
    o.x = pack4_fp8(f[0], f[1], f[2], f[3]);
    o.y = pack4_fp8(f[4], f[5], f[6], f[7]);
    ((uint2*)out)[i] = o;
}

// ---------------- output GEMM via MFMA f16 (K=64): out = relu(h) @ W_out^T + b ----------------

__global__ __launch_bounds__(256) void gemm2_mfma(const float* __restrict__ h,
                                                  const _Float16* __restrict__ W2o,
                                                  const float* __restrict__ bias,
                                                  float* __restrict__ out) {
    __shared__ _Float16 W2[8 * 64 * 8];   // 8 KB
    int t = threadIdx.x;
    for (int i = t; i < 512; i += 256)
        *(half8*)&W2[(size_t)i * 8] = *(const half8*)&W2o[(size_t)i * 8];
    __syncthreads();

    int lane = t & 63;
    int w = t >> 6;
    int r16 = lane & 15, kg = lane >> 4;
    int row0 = blockIdx.x * 128;
    int rowA = row0 + w * 32 + r16;
    int rowB = rowA + 16;
    int rA = rowA < NN ? rowA : NN - 1;
    int rB = rowB < NN ? rowB : NN - 1;
    const float* pa = &h[(size_t)rA * 64 + kg * 8];
    const float* pb = &h[(size_t)rB * 64 + kg * 8];

    f32x4 acc[2][4];
#pragma unroll
    for (int mt = 0; mt < 2; mt++)
#pragma unroll
        for (int nt = 0; nt < 4; nt++) acc[mt][nt] = (f32x4){0.f, 0.f, 0.f, 0.f};

#pragma unroll
    for (int ks = 0; ks < 2; ks++) {
        float4 va0 = *(const float4*)(pa + ks * 32);
        float4 va1 = *(const float4*)(pa + ks * 32 + 4);
        float4 vb0 = *(const float4*)(pb + ks * 32);
        float4 vb1 = *(const float4*)(pb + ks * 32 + 4);
        _Float16 a0h[8] = {(_Float16)fmaxf(va0.x, 0.f), (_Float16)fmaxf(va0.y, 0.f),
                           (_Float16)fmaxf(va0.z, 0.f), (_Float16)fmaxf(va0.w, 0.f),
                           (_Float16)fmaxf(va1.x, 0.f), (_Float16)fmaxf(va1.y, 0.f),
                           (_Float16)fmaxf(va1.z, 0.f), (_Float16)fmaxf(va1.w, 0.f)};
        _Float16 a1h[8] = {(_Float16)fmaxf(vb0.x, 0.f), (_Float16)fmaxf(vb0.y, 0.f),
                           (_Float16)fmaxf(vb0.z, 0.f), (_Float16)fmaxf(vb0.w, 0.f),
                           (_Float16)fmaxf(vb1.x, 0.f), (_Float16)fmaxf(vb1.y, 0.f),
                           (_Float16)fmaxf(vb1.z, 0.f), (_Float16)fmaxf(vb1.w, 0.f)};
        half8 a0 = *(half8*)a0h;
        half8 a1 = *(half8*)a1h;
        int kgg = ks * 4 + kg;
#pragma unroll
        for (int nt = 0; nt < 4; nt++) {
            int nidx = nt * 16 + r16;
            int slot = (kgg << 6) + (nidx ^ ((kgg & 3) << 2));
            half8 bfr = *(half8*)&W2[(size_t)slot * 8];
            acc[0][nt] = __builtin_amdgcn_mfma_f32_16x16x32_f16(a0, bfr, acc[0][nt], 0, 0, 0);
            acc[1][nt] = __builtin_amdgcn_mfma_f32_16x16x32_f16(a1, bfr, acc[1][nt], 0, 0, 0);
        }
    }

#pragma unroll
    for (int mt = 0; mt < 2; mt++)
#pragma unroll
        for (int nt = 0; nt < 4; nt++) {
            int colj = nt * 16 + r16;
            float bv = bias[colj];
#pragma unroll
            for (int r = 0; r < 4; r++) {
                int row = row0 + w * 32 + mt * 16 + kg * 4 + r;
                if (row < NN)
                    out[(size_t)row * 64 + colj] = acc[mt][nt][r] + bv;
            }
        }
}

// ---------------- APPNP propagation: fp8 state, 8B slots, MLP-4 rounds ----------------
// R19 arithmetic: 58us = 139K cyc/CU vs ~14K (L2-BW) / ~45K (L3-BW) -> LATENCY-bound.
// Little's law: ~24 waves/CU x 2 outstanding = 50 reqs @ ~750cyc = matches observed.
// Fix: 32 edges/round, 4 independent gathers issued before any accumulate (MLP 2->4).
// R20 counter-lesson: do NOT split features/duplicate edge work for L2 residency.

template <bool FINAL>
__global__ __launch_bounds__(256) void appnp_prop_8(const unsigned char* __restrict__ gcur8,
                                                    void* __restrict__ gnext,
                                                    const __half* __restrict__ g0h,
                                                    const float* __restrict__ dinv,
                                                    const int* __restrict__ deg,
                                                    const int* __restrict__ col) {
    int wid = (blockIdx.x * 256 + threadIdx.x) >> 6;   // node id
    int lane = threadIdx.x & 63;
    if (wid >= NN) return;
    int eg = lane >> 3;    // edge group 0..7
    int q  = lane & 7;     // 8B slot (feats 8q..8q+7)
    const uint2* gc = (const uint2*)gcur8;   // row = 8 uint2 (64 fp8)

    float acc[8];
#pragma unroll
    for (int j = 0; j < 8; j++) acc[j] = 0.f;

    int dg = deg[wid]; if (dg > CAP) dg = CAP;
    int e0 = wid * CAP;
    int end = e0 + dg;
    for (int p = e0; p < end; p += 32) {   // 32 edges/round, 4 gathers in flight
        int i0 = p + eg, i1 = p + 8 + eg, i2 = p + 16 + eg, i3 = p + 24 + eg;
        float m0 = (i0 < end) ? 1.f : 0.f;
        float m1 = (i1 < end) ? 1.f : 0.f;
        float m2 = (i2 < end) ? 1.f : 0.f;
        float m3 = (i3 < end) ? 1.f : 0.f;
        int s0 = col[(i0 < end) ? i0 : end - 1];
        int s1 = col[(i1 < end) ? i1 : end - 1];
        int s2 = col[(i2 < end) ? i2 : end - 1];
        int s3 = col[(i3 < end) ? i3 : end - 1];
        uint2 r0 = gc[(size_t)s0 * 8 + q];
        uint2 r1 = gc[(size_t)s1 * 8 + q];
        uint2 r2 = gc[(size_t)s2 * 8 + q];
        uint2 r3 = gc[(size_t)s3 * 8 + q];
        acc8_fp8(r0, m0, acc);
        acc8_fp8(r1, m1, acc);
        acc8_fp8(r2, m2, acc);
        acc8_fp8(r3, m3, acc);
    }

    // butterfly reduce across the 8 edge groups (lane bits 3,4,5)
#pragma unroll
    for (int st = 8; st < 64; st <<= 1) {
#pragma unroll
        for (int j = 0; j < 8; j++) acc[j] += __shfl(acc[j], lane ^ st);
    }

    if (eg == 0) {   // lanes 0..7, lane == q; 8 feats each
        float di = dinv[wid];
        float k = (1.f - ALPHA) * di * di;
        // self term (fp8)
        uint2 sraw = gc[(size_t)wid * 8 + q];
        float sf[8];
        {
            auto l0 = __builtin_amdgcn_cvt_pk_f32_fp8(sraw.x, false);
            auto h0 = __builtin_amdgcn_cvt_pk_f32_fp8(sraw.x, true);
            auto l1 = __builtin_amdgcn_cvt_pk_f32_fp8(sraw.y, false);
            auto h1 = __builtin_amdgcn_cvt_pk_f32_fp8(sraw.y, true);
            sf[0] = l0[0]; sf[1] = l0[1]; sf[2] = h0[0]; sf[3] = h0[1];
            sf[4] = l1[0]; sf[5] = l1[1]; sf[6] = h1[0]; sf[7] = h1[1];
        }
        // anchor term (fp16)
        float zf[8];
        {
            float4 zraw = *(const float4*)&g0h[(size_t)wid * 64 + q * 8];
            const __half2* zh = (const __half2*)&zraw;
#pragma unroll
            for (int j = 0; j < 4; j++) {
                float2 v = __half22float2(zh[j]);
                zf[2 * j] = v.x; zf[2 * j + 1] = v.y;
            }
        }
        float g[8];
#pragma unroll
        for (int j = 0; j < 8; j++)
            g[j] = k * (acc[j] + sf[j]) + ALPHA * zf[j];

        if (FINAL) {   // h = g/dinv, fp32 row-major
            float inv = 1.f / di;
            float* ho = (float*)gnext;
            float4 o0 = make_float4(g[0] * inv, g[1] * inv, g[2] * inv, g[3] * inv);
            float4 o1 = make_float4(g[4] * inv, g[5] * inv, g[6] * inv, g[7] * inv);
            *(float4*)&ho[(size_t)wid * 64 + q * 8]     = o0;
            *(float4*)&ho[(size_t)wid * 64 + q * 8 + 4] = o1;
        } else {
            uint2 o;
            o.x = pack4_fp8(g[0], g[1], g[2], g[3]);
            o.y = pack4_fp8(g[4], g[5], g[6], g[7]);
            ((uint2*)gnext)[(size_t)wid * 8 + q] = o;
        }
    }
}

// ---------------- launch ----------------

extern "C" void kernel_launch(void* const* d_in, const int* in_sizes, int n_in,
                              void* d_out, int out_size, void* d_ws, size_t ws_size,
                              hipStream_t stream) {
    const float* x    = (const float*)d_in[0];
    const int*  ei    = (const int*)d_in[1];      // harness converts int64 -> int32
    const float* W_in = (const float*)d_in[2];
    const float* b_in = (const float*)d_in[3];
    const float* W_out= (const float*)d_in[4];
    const float* b_out= (const float*)d_in[5];
    float* out = (float*)d_out;

    char* ws = (char*)d_ws;
    size_t off = 0;
    auto alloc = [&](size_t bytes) -> void* {
        void* p = ws + off;
        off = (off + bytes + 255) & ~(size_t)255;
        return p;
    };
    int*      deg  = (int*)    alloc((size_t)NN * 4);
    float*    dinv = (float*)  alloc((size_t)NN * 4);
    int*      cntg = (int*)    alloc((size_t)NB * 256 * 4);       // 256 KB
    _Float16* W2g  = (_Float16*)alloc((size_t)32 * 64 * 8 * 2);   // 32 KB packed W_in
    _Float16* W2o  = (_Float16*)alloc((size_t)8 * 64 * 8 * 2);    // 8 KB packed W_out
    int*      col  = (int*)    alloc((size_t)NN * CAP * 4);       // 32 MB
    __half*   g0h  = (__half*) alloc((size_t)NN * HDIM * 2);      // 12.8 MB fp16 anchor
    unsigned char* g08 = (unsigned char*)alloc((size_t)NN * HDIM); // 6.4 MB fp8
    unsigned char* gA8 = (unsigned char*)alloc((size_t)NN * HDIM); // 6.4 MB
    unsigned char* gB8 = (unsigned char*)alloc((size_t)NN * HDIM); // 6.4 MB
    // pairs (25.2MB) aliases the g region: dead before gemm1 writes g0h
    unsigned* pairs = (unsigned*)g0h;

    // CSR build: 2 kernels, zero global atomics, deg/dinv emitted by stage B
    bucket_edges<<<256, 1024, 0, stream>>>(ei, pairs, cntg);
    fill_bucket<<<NB, 1024, 0, stream>>>(pairs, cntg, col, deg, dinv);

    // weight packs
    prep_w<<<8, 256, 0, stream>>>(W_in, W2g, 32, 256);
    prep_w<<<2, 256, 0, stream>>>(W_out, W2o, 8, 64);

    // g0 = fp16((x @ W_in^T + b_in) * dinv[row]) via MFMA f16; fp8 copy for gathering
    gemm1_mfma<<<(NN + 127) / 128, 256, 0, stream>>>(x, W2g, b_in, dinv, (_Float16*)g0h);
    cvt_fp16_fp8<<<(NN * 8 + 255) / 256, 256, 0, stream>>>(g0h, g08);

    // K=4 APPNP iterations on fp8 state; 4th writes fp32 h into d_out
    const int pgrid = (NN * HDIM) / 256;   // 25000 blocks, 1 wave per node
    appnp_prop_8<false><<<pgrid, 256, 0, stream>>>(g08, gA8, g0h, dinv, deg, col);
    appnp_prop_8<false><<<pgrid, 256, 0, stream>>>(gA8, gB8, g0h, dinv, deg, col);
    appnp_prop_8<false><<<pgrid, 256, 0, stream>>>(gB8, gA8, g0h, dinv, deg, col);
    appnp_prop_8<true ><<<pgrid, 256, 0, stream>>>(gA8, out, g0h, dinv, deg, col);

    // out = relu(h) @ W_out^T + b_out via MFMA f16 (in-place safe per wave-span analysis)
    gemm2_mfma<<<(NN + 127) / 128, 256, 0, stream>>>(out, W2o, b_out, out);
}